// Round 1
// baseline (62.739 us; speedup 1.0000x reference)
//
#include <hip/hip_runtime.h>
#include <math.h>

// Problem constants (from reference)
#define NUM_DEVICES   50
#define HW_DIM        10
#define NUM_INTERVALS 101
#define ROW_DIM       30

// One wave does the whole op:
//  - lanes 0..49: sim[e] = dot(hw, hw_emb[e]) / sqrt(10); s = sin(sim)
//  - full-wave shuffle max/sum reduce -> softmax gate
//  - gate -> LDS
//  - lanes 0..29: out[d] = sum_e gate[e] * expert_emb[e, idx, d]
__global__ __launch_bounds__(64)
void mhn_kernel(const float* __restrict__ x,
                const float* __restrict__ hw,
                const float* __restrict__ hw_emb,
                const float* __restrict__ expert_emb,
                float* __restrict__ out)
{
    __shared__ float gate_s[NUM_DEVICES];
    const int lane = threadIdx.x;  // 0..63, single wave

    // --- sim + sin ---
    float s = -INFINITY;
    if (lane < NUM_DEVICES) {
        float acc = 0.f;
#pragma unroll
        for (int j = 0; j < HW_DIM; ++j)
            acc = fmaf(hw[j], hw_emb[lane * HW_DIM + j], acc);
        // 1/sqrt(10)
        s = sinf(acc * 0.31622776601683794f);
    }

    // --- softmax over 64 lanes (inactive lanes: -inf / 0) ---
    float m = s;
#pragma unroll
    for (int off = 32; off >= 1; off >>= 1)
        m = fmaxf(m, __shfl_xor(m, off, 64));

    float e = (lane < NUM_DEVICES) ? expf(s - m) : 0.f;
    float sum = e;
#pragma unroll
    for (int off = 32; off >= 1; off >>= 1)
        sum += __shfl_xor(sum, off, 64);

    if (lane < NUM_DEVICES) gate_s[lane] = e / sum;
    __syncthreads();

    // --- gather row at idx and weighted-sum ---
    const int idx = (int)rintf(x[0] * (float)(NUM_INTERVALS - 1));  // round half-to-even, matches jnp.round
    if (lane < ROW_DIM) {
        const float* rows = expert_emb + (size_t)idx * ROW_DIM + lane;
        float acc = 0.f;
#pragma unroll 10
        for (int ee = 0; ee < NUM_DEVICES; ++ee)
            acc = fmaf(gate_s[ee], rows[(size_t)ee * (NUM_INTERVALS * ROW_DIM)], acc);
        out[lane] = acc;
    }
}

extern "C" void kernel_launch(void* const* d_in, const int* in_sizes, int n_in,
                              void* d_out, int out_size, void* d_ws, size_t ws_size,
                              hipStream_t stream)
{
    const float* x          = (const float*)d_in[0];
    const float* hw         = (const float*)d_in[1];
    const float* hw_emb     = (const float*)d_in[2];
    const float* expert_emb = (const float*)d_in[3];
    float* out              = (float*)d_out;

    mhn_kernel<<<1, 64, 0, stream>>>(x, hw, hw_emb, expert_emb, out);
}

// Round 2
// 61.795 us; speedup vs baseline: 1.0153x; 1.0153x over previous
//
#include <hip/hip_runtime.h>
#include <math.h>

// Problem constants (from reference)
#define NUM_DEVICES   50
#define HW_DIM        10
#define NUM_INTERVALS 101
#define ROW_DIM       30
#define EXPERT_STRIDE (NUM_INTERVALS * ROW_DIM)  // 3030 floats per device

// Single wave, latency-optimized:
//  - issue x load + hw/hw_emb loads immediately (independent)
//  - as soon as x lands, issue all 50 expert_emb column loads (in-flight
//    during the softmax math)
//  - softmax entirely in registers (shuffle butterfly), gate broadcast via
//    __shfl from lane e (no LDS, no barrier), normalize once at the end.
__global__ __launch_bounds__(64)
void mhn_kernel(const float* __restrict__ x,
                const float* __restrict__ hw,
                const float* __restrict__ hw_emb,
                const float* __restrict__ expert_emb,
                float* __restrict__ out)
{
    const int lane = threadIdx.x;  // 0..63, single wave

    // --- issue independent front loads ---
    const float xv = x[0];  // gates idx -> expert loads

    float hw_r[HW_DIM];
    float he_r[HW_DIM];
    const float* he = hw_emb + (lane < NUM_DEVICES ? lane : 0) * HW_DIM;
#pragma unroll
    for (int j = 0; j < HW_DIM; ++j) hw_r[j] = hw[j];      // uniform -> s_load
#pragma unroll
    for (int j = 0; j < HW_DIM; ++j) he_r[j] = he[j];

    // --- idx + expert-row loads (issued before softmax math) ---
    const int idx = (int)rintf(xv * (float)(NUM_INTERVALS - 1));  // half-to-even == jnp.round
    const int d = (lane < ROW_DIM) ? lane : 0;
    const float* rowp = expert_emb + (size_t)idx * ROW_DIM + d;
    float r[NUM_DEVICES];
#pragma unroll
    for (int e = 0; e < NUM_DEVICES; ++e)
        r[e] = rowp[(size_t)e * EXPERT_STRIDE];

    // --- sim + sin (hw/hw_emb loads have had time to land) ---
    float acc = 0.f;
#pragma unroll
    for (int j = 0; j < HW_DIM; ++j)
        acc = fmaf(hw_r[j], he_r[j], acc);
    const float s = (lane < NUM_DEVICES)
                        ? sinf(acc * 0.31622776601683794f)  // 1/sqrt(10)
                        : -INFINITY;

    // --- softmax over the wave, in registers ---
    float m = s;
#pragma unroll
    for (int off = 32; off >= 1; off >>= 1)
        m = fmaxf(m, __shfl_xor(m, off, 64));

    const float ev = (lane < NUM_DEVICES) ? expf(s - m) : 0.f;
    float sum = ev;
#pragma unroll
    for (int off = 32; off >= 1; off >>= 1)
        sum += __shfl_xor(sum, off, 64);

    // --- weighted sum; gate broadcast via readlane-shfl, normalize once ---
    float o = 0.f;
#pragma unroll
    for (int e = 0; e < NUM_DEVICES; ++e) {
        const float g = __shfl(ev, e, 64);  // compile-time lane -> v_readlane
        o = fmaf(g, r[e], o);
    }
    if (lane < ROW_DIM)
        out[lane] = o / sum;
}

extern "C" void kernel_launch(void* const* d_in, const int* in_sizes, int n_in,
                              void* d_out, int out_size, void* d_ws, size_t ws_size,
                              hipStream_t stream)
{
    const float* x          = (const float*)d_in[0];
    const float* hw         = (const float*)d_in[1];
    const float* hw_emb     = (const float*)d_in[2];
    const float* expert_emb = (const float*)d_in[3];
    float* out              = (float*)d_out;

    mhn_kernel<<<1, 64, 0, stream>>>(x, hw, hw_emb, expert_emb, out);
}